// Round 4
// baseline (890.883 us; speedup 1.0000x reference)
//
#include <hip/hip_runtime.h>
#include <hip/hip_bf16.h>

#define TOKENS 2048
#define HDIM 1024
#define IDIM 512
#define NEXP 64
#define TOPKK 8
#define NGRP 8
#define TOPG 4

typedef __bf16 bf16_t;
typedef __bf16 bf16x8 __attribute__((ext_vector_type(8)));
typedef __bf16 bf16x4 __attribute__((ext_vector_type(4)));
typedef float f32x4 __attribute__((ext_vector_type(4)));

// XOR swizzle: kills 32-way bank conflict on 128B-stride row-major LDS tiles
#define SWZ(r, b) ((b) ^ (((r) & 7) << 4))

__device__ inline bf16x8 pack_bf16x8(float4 a, float4 b) {
  bf16x8 r;
  r[0] = (bf16_t)a.x; r[1] = (bf16_t)a.y; r[2] = (bf16_t)a.z; r[3] = (bf16_t)a.w;
  r[4] = (bf16_t)b.x; r[5] = (bf16_t)b.y; r[6] = (bf16_t)b.z; r[7] = (bf16_t)b.w;
  return r;
}

// ---------------- x fp32 -> bf16 ----------------
__global__ __launch_bounds__(256) void cvt_x_kernel(const float* __restrict__ x,
                                                    bf16_t* __restrict__ xb) {
  int i = blockIdx.x * 256 + threadIdx.x;  // each handles 4 floats
  float4 v = reinterpret_cast<const float4*>(x)[i];
  bf16x4 o;
  o[0] = (bf16_t)v.x; o[1] = (bf16_t)v.y; o[2] = (bf16_t)v.z; o[3] = (bf16_t)v.w;
  reinterpret_cast<bf16x4*>(xb)[i] = o;
}

// ---------------- router: gate GEMV + grouped top-k + expert lists ----------------
__global__ __launch_bounds__(256) void router_kernel(
    const float* __restrict__ x, const float* __restrict__ gw,
    const float* __restrict__ bias, int* __restrict__ counts,
    int* __restrict__ tok_list, int* __restrict__ dst_list,
    float* __restrict__ wgt_list) {
  int t0 = blockIdx.x * 16;  // 16 tokens per block
  int tid = threadIdx.x;
  int e = tid & 63;
  int sub = tid >> 6;  // 0..3 ; this thread computes logits[e] for tokens t0+sub*4 .. +3

  const float4* gwe = reinterpret_cast<const float4*>(gw + (size_t)e * HDIM);
  const float4* x0 = reinterpret_cast<const float4*>(x + (size_t)(t0 + sub * 4 + 0) * HDIM);
  const float4* x1 = reinterpret_cast<const float4*>(x + (size_t)(t0 + sub * 4 + 1) * HDIM);
  const float4* x2 = reinterpret_cast<const float4*>(x + (size_t)(t0 + sub * 4 + 2) * HDIM);
  const float4* x3 = reinterpret_cast<const float4*>(x + (size_t)(t0 + sub * 4 + 3) * HDIM);
  float a0 = 0.f, a1 = 0.f, a2 = 0.f, a3 = 0.f;
  for (int h = 0; h < HDIM / 4; ++h) {
    float4 g = gwe[h];
    float4 v;
    v = x0[h]; a0 += g.x * v.x + g.y * v.y + g.z * v.z + g.w * v.w;
    v = x1[h]; a1 += g.x * v.x + g.y * v.y + g.z * v.z + g.w * v.w;
    v = x2[h]; a2 += g.x * v.x + g.y * v.y + g.z * v.z + g.w * v.w;
    v = x3[h]; a3 += g.x * v.x + g.y * v.y + g.z * v.z + g.w * v.w;
  }
  __shared__ float sc[16][64];
  sc[sub * 4 + 0][e] = a0;
  sc[sub * 4 + 1][e] = a1;
  sc[sub * 4 + 2][e] = a2;
  sc[sub * 4 + 3][e] = a3;
  __syncthreads();

  int lane = tid & 63;
  int wv = tid >> 6;
  for (int it = 0; it < 4; ++it) {
    int tt = wv * 4 + it;
    int t = t0 + tt;
    float logit = sc[tt][lane];
    float score = 1.0f / (1.0f + __expf(-logit));  // sigmoid
    float s = score + bias[lane];                  // selection score

    // top-2 per group of 8 lanes (butterfly merge of (m1,m2) pairs)
    float m1 = s, m2 = -INFINITY;
#pragma unroll
    for (int off = 1; off < 8; off <<= 1) {
      float o1 = __shfl_xor(m1, off);
      float o2 = __shfl_xor(m2, off);
      float hi = fmaxf(m1, o1);
      float lo = fminf(m1, o1);
      m2 = fmaxf(lo, fmaxf(m2, o2));
      m1 = hi;
    }
    float gscore = m1 + m2;  // identical across the 8 lanes of the group
    int g = lane >> 3;
    int grank = 0;
#pragma unroll
    for (int gg = 0; gg < 8; ++gg) {
      float og = __shfl(gscore, gg << 3);
      grank += ((og > gscore) || (og == gscore && gg < g)) ? 1 : 0;
    }
    float masked = (grank < TOPG) ? s : -INFINITY;

    // rank among 64 (descending, ties -> lower lane wins)
    int rank = 0;
    for (int l = 0; l < 64; ++l) {
      float ov = __shfl(masked, l);
      rank += ((ov > masked) || (ov == masked && l < lane)) ? 1 : 0;
    }
    bool sel = (rank < TOPKK) && (masked > -INFINITY);
    float part = sel ? score : 0.0f;
#pragma unroll
    for (int off = 32; off > 0; off >>= 1) part += __shfl_xor(part, off);
    if (sel) {
      int slot = atomicAdd(&counts[lane], 1);
      tok_list[lane * TOKENS + slot] = t;
      dst_list[lane * TOKENS + slot] = t * TOPKK + rank;  // compact h-row index
      wgt_list[lane * TOKENS + slot] = score / part;      // renormalized raw score
    }
  }
}

// ---------------- GEMM1: h = silu(x@Wg^T) * (x@Wu^T), per expert ----------------
// block: 256 thr (4 waves). tile = [256 tokens x 64 inter-cols], K=1024 staged BK=64.
__global__ __launch_bounds__(256, 2) void gemm1_kernel(
    const bf16_t* __restrict__ xb, const float* __restrict__ w13,
    const int* __restrict__ counts, const int* __restrict__ tok_list,
    const int* __restrict__ dst_list, bf16_t* __restrict__ hbuf) {
  int e = blockIdx.z;
  int cnt = counts[e];
  int row0 = blockIdx.y * 256;
  if (row0 >= cnt) return;
  int rows = cnt - row0;
  if (rows > 256) rows = 256;
  int n0 = blockIdx.x * 64;  // over IDIM

  __shared__ alignas(16) char As[256 * 128];
  __shared__ alignas(16) char Bg[64 * 128];
  __shared__ alignas(16) char Bu[64 * 128];
  __shared__ int dstS[256];

  int tid = threadIdx.x;
  int tok = -1;
  if (tid < rows) {
    tok = tok_list[e * TOKENS + row0 + tid];
    dstS[tid] = dst_list[e * TOKENS + row0 + tid];
  }
  const bf16_t* xrow = (tok >= 0) ? (xb + (size_t)tok * HDIM) : (const bf16_t*)0;

  int lane = tid & 63;
  int wv = tid >> 6;

  f32x4 accg[4][4], accu[4][4];
#pragma unroll
  for (int i = 0; i < 4; ++i)
#pragma unroll
    for (int j = 0; j < 4; ++j) {
      accg[i][j] = f32x4{0.f, 0.f, 0.f, 0.f};
      accu[i][j] = f32x4{0.f, 0.f, 0.f, 0.f};
    }

  const float* w13e = w13 + (size_t)e * (2 * IDIM) * HDIM;
  int bn = tid >> 2;  // 0..63 : B row
  int bq = tid & 3;   // quarter of 64 k-elems
  const float* gsrc = w13e + (size_t)(n0 + bn) * HDIM + bq * 16;
  const float* usrc = w13e + (size_t)(IDIM + n0 + bn) * HDIM + bq * 16;

  for (int kt = 0; kt < 16; ++kt) {
    __syncthreads();
    // ---- stage A (gathered token rows, bf16) ----
    if (tid < rows) {
      const bf16_t* src = xrow + kt * 64;
#pragma unroll
      for (int j = 0; j < 8; ++j) {
        bf16x8 v = *reinterpret_cast<const bf16x8*>(src + j * 8);
        *reinterpret_cast<bf16x8*>(&As[SWZ(tid, tid * 128 + j * 16)]) = v;
      }
    }
    // ---- stage Bg / Bu (fp32 -> bf16 inline) ----
    {
      const float4* s4 = reinterpret_cast<const float4*>(gsrc + kt * 64);
      float4 f0 = s4[0], f1 = s4[1], f2 = s4[2], f3 = s4[3];
      int b0 = bn * 128 + bq * 32;
      *reinterpret_cast<bf16x8*>(&Bg[SWZ(bn, b0)]) = pack_bf16x8(f0, f1);
      *reinterpret_cast<bf16x8*>(&Bg[SWZ(bn, b0 + 16)]) = pack_bf16x8(f2, f3);
      const float4* u4 = reinterpret_cast<const float4*>(usrc + kt * 64);
      f0 = u4[0]; f1 = u4[1]; f2 = u4[2]; f3 = u4[3];
      *reinterpret_cast<bf16x8*>(&Bu[SWZ(bn, b0)]) = pack_bf16x8(f0, f1);
      *reinterpret_cast<bf16x8*>(&Bu[SWZ(bn, b0 + 16)]) = pack_bf16x8(f2, f3);
    }
    __syncthreads();
    // ---- compute 2 k-steps of 32 ----
#pragma unroll
    for (int ks = 0; ks < 2; ++ks) {
      int kb2 = (ks * 32 + ((lane >> 4) << 3)) * 2;  // byte offset of k within row
      bf16x8 a[4], bg[4], bu[4];
#pragma unroll
      for (int i = 0; i < 4; ++i) {
        int r = wv * 64 + i * 16 + (lane & 15);
        a[i] = *reinterpret_cast<const bf16x8*>(&As[SWZ(r, r * 128 + kb2)]);
      }
#pragma unroll
      for (int j = 0; j < 4; ++j) {
        int n = j * 16 + (lane & 15);
        bg[j] = *reinterpret_cast<const bf16x8*>(&Bg[SWZ(n, n * 128 + kb2)]);
        bu[j] = *reinterpret_cast<const bf16x8*>(&Bu[SWZ(n, n * 128 + kb2)]);
      }
#pragma unroll
      for (int i = 0; i < 4; ++i)
#pragma unroll
        for (int j = 0; j < 4; ++j) {
          accg[i][j] = __builtin_amdgcn_mfma_f32_16x16x32_bf16(a[i], bg[j], accg[i][j], 0, 0, 0);
          accu[i][j] = __builtin_amdgcn_mfma_f32_16x16x32_bf16(a[i], bu[j], accu[i][j], 0, 0, 0);
        }
    }
  }
  // ---- epilogue: SwiGLU, store h as bf16 ----
#pragma unroll
  for (int i = 0; i < 4; ++i) {
    int mbase = wv * 64 + i * 16 + ((lane >> 4) << 2);
#pragma unroll
    for (int r = 0; r < 4; ++r) {
      int m = mbase + r;
      if (m < rows) {
        int dst = dstS[m];
        bf16_t* hrow = hbuf + (size_t)dst * IDIM + n0;
#pragma unroll
        for (int j = 0; j < 4; ++j) {
          float gv = accg[i][j][r];
          float uv = accu[i][j][r];
          float hv = (gv / (1.0f + __expf(-gv))) * uv;
          hrow[j * 16 + (lane & 15)] = (bf16_t)hv;
        }
      }
    }
  }
}

// ---------------- GEMM2: y += wgt * (h @ w2^T), per expert ----------------
__global__ __launch_bounds__(256, 2) void gemm2_kernel(
    const bf16_t* __restrict__ hbuf, const float* __restrict__ w2,
    const int* __restrict__ counts, const int* __restrict__ tok_list,
    const int* __restrict__ dst_list, const float* __restrict__ wgt_list,
    float* __restrict__ y) {
  int e = blockIdx.z;
  int cnt = counts[e];
  int row0 = blockIdx.y * 256;
  if (row0 >= cnt) return;
  int rows = cnt - row0;
  if (rows > 256) rows = 256;
  int n0 = blockIdx.x * 64;  // over HDIM

  __shared__ alignas(16) char As[256 * 128];
  __shared__ alignas(16) char Bs[64 * 128];
  __shared__ int tokS[256];
  __shared__ float wS[256];

  int tid = threadIdx.x;
  int dst = -1;
  if (tid < rows) {
    tokS[tid] = tok_list[e * TOKENS + row0 + tid];
    dst = dst_list[e * TOKENS + row0 + tid];
    wS[tid] = wgt_list[e * TOKENS + row0 + tid];
  }
  const bf16_t* hrow = (dst >= 0) ? (hbuf + (size_t)dst * IDIM) : (const bf16_t*)0;

  int lane = tid & 63;
  int wv = tid >> 6;
  f32x4 acc[4][4];
#pragma unroll
  for (int i = 0; i < 4; ++i)
#pragma unroll
    for (int j = 0; j < 4; ++j) acc[i][j] = f32x4{0.f, 0.f, 0.f, 0.f};

  const float* w2e = w2 + (size_t)e * HDIM * IDIM;
  int bn = tid >> 2;
  int bq = tid & 3;
  const float* bsrc = w2e + (size_t)(n0 + bn) * IDIM + bq * 16;

  for (int kt = 0; kt < 8; ++kt) {  // K = 512
    __syncthreads();
    if (tid < rows) {
      const bf16_t* src = hrow + kt * 64;
#pragma unroll
      for (int j = 0; j < 8; ++j) {
        bf16x8 v = *reinterpret_cast<const bf16x8*>(src + j * 8);
        *reinterpret_cast<bf16x8*>(&As[SWZ(tid, tid * 128 + j * 16)]) = v;
      }
    }
    {
      const float4* s4 = reinterpret_cast<const float4*>(bsrc + kt * 64);
      float4 f0 = s4[0], f1 = s4[1], f2 = s4[2], f3 = s4[3];
      int b0 = bn * 128 + bq * 32;
      *reinterpret_cast<bf16x8*>(&Bs[SWZ(bn, b0)]) = pack_bf16x8(f0, f1);
      *reinterpret_cast<bf16x8*>(&Bs[SWZ(bn, b0 + 16)]) = pack_bf16x8(f2, f3);
    }
    __syncthreads();
#pragma unroll
    for (int ks = 0; ks < 2; ++ks) {
      int kb2 = (ks * 32 + ((lane >> 4) << 3)) * 2;
      bf16x8 a[4], b[4];
#pragma unroll
      for (int i = 0; i < 4; ++i) {
        int r = wv * 64 + i * 16 + (lane & 15);
        a[i] = *reinterpret_cast<const bf16x8*>(&As[SWZ(r, r * 128 + kb2)]);
      }
#pragma unroll
      for (int j = 0; j < 4; ++j) {
        int n = j * 16 + (lane & 15);
        b[j] = *reinterpret_cast<const bf16x8*>(&Bs[SWZ(n, n * 128 + kb2)]);
      }
#pragma unroll
      for (int i = 0; i < 4; ++i)
#pragma unroll
        for (int j = 0; j < 4; ++j)
          acc[i][j] = __builtin_amdgcn_mfma_f32_16x16x32_bf16(a[i], b[j], acc[i][j], 0, 0, 0);
    }
  }
  // ---- epilogue: scaled atomic accumulate into y ----
#pragma unroll
  for (int i = 0; i < 4; ++i) {
    int mbase = wv * 64 + i * 16 + ((lane >> 4) << 2);
#pragma unroll
    for (int r = 0; r < 4; ++r) {
      int m = mbase + r;
      if (m < rows) {
        float wgt = wS[m];
        float* yrow = y + (size_t)tokS[m] * HDIM + n0;
#pragma unroll
        for (int j = 0; j < 4; ++j) {
          atomicAdd(&yrow[j * 16 + (lane & 15)], acc[i][j][r] * wgt);
        }
      }
    }
  }
}

extern "C" void kernel_launch(void* const* d_in, const int* in_sizes, int n_in,
                              void* d_out, int out_size, void* d_ws, size_t ws_size,
                              hipStream_t stream) {
  const float* x = (const float*)d_in[0];
  const float* gw = (const float*)d_in[1];
  const float* bias = (const float*)d_in[2];
  const float* w13 = (const float*)d_in[3];
  const float* w2 = (const float*)d_in[4];
  float* y = (float*)d_out;

  char* ws = (char*)d_ws;
  const size_t LIST = (size_t)NEXP * TOKENS * 4;  // 512 KB
  int* counts = (int*)ws;                         // 1 KB reserved
  int* tok_list = (int*)(ws + 1024);
  int* dst_list = (int*)(ws + 1024 + LIST);
  float* wgt_list = (float*)(ws + 1024 + 2 * LIST);
  bf16_t* xb = (bf16_t*)(ws + 1024 + 3 * LIST);                          // 4 MB
  bf16_t* hbuf = (bf16_t*)(ws + 1024 + 3 * LIST + (size_t)TOKENS * HDIM * 2);  // 16 MB

  hipMemsetAsync(counts, 0, 1024, stream);
  hipMemsetAsync(y, 0, (size_t)TOKENS * HDIM * sizeof(float), stream);
  cvt_x_kernel<<<dim3(TOKENS * HDIM / 4 / 256), 256, 0, stream>>>(x, xb);
  router_kernel<<<dim3(TOKENS / 16), 256, 0, stream>>>(x, gw, bias, counts, tok_list,
                                                       dst_list, wgt_list);
  gemm1_kernel<<<dim3(IDIM / 64, 8, NEXP), 256, 0, stream>>>(xb, w13, counts, tok_list,
                                                             dst_list, hbuf);
  gemm2_kernel<<<dim3(HDIM / 64, 8, NEXP), 256, 0, stream>>>(hbuf, w2, counts, tok_list,
                                                             dst_list, wgt_list, y);
}

// Round 5
// 890.230 us; speedup vs baseline: 1.0007x; 1.0007x over previous
//
#include <hip/hip_runtime.h>
#include <hip/hip_bf16.h>

#define TOKENS 2048
#define HDIM 1024
#define IDIM 512
#define NEXP 64
#define TOPKK 8
#define NGRP 8
#define TOPG 4

typedef __bf16 bf16_t;
typedef __bf16 bf16x8 __attribute__((ext_vector_type(8)));
typedef __bf16 bf16x4 __attribute__((ext_vector_type(4)));
typedef float f32x4 __attribute__((ext_vector_type(4)));

// XOR swizzle: kills 32-way bank conflict on 128B-stride row-major LDS tiles
#define SWZ(r, b) ((b) ^ (((r) & 7) << 4))

__device__ inline bf16x8 pack_bf16x8(float4 a, float4 b) {
  bf16x8 r;
  r[0] = (bf16_t)a.x; r[1] = (bf16_t)a.y; r[2] = (bf16_t)a.z; r[3] = (bf16_t)a.w;
  r[4] = (bf16_t)b.x; r[5] = (bf16_t)b.y; r[6] = (bf16_t)b.z; r[7] = (bf16_t)b.w;
  return r;
}

// ---------------- x fp32 -> bf16 ----------------
__global__ __launch_bounds__(256) void cvt_x_kernel(const float* __restrict__ x,
                                                    bf16_t* __restrict__ xb) {
  int i = blockIdx.x * 256 + threadIdx.x;  // each handles 4 floats
  float4 v = reinterpret_cast<const float4*>(x)[i];
  bf16x4 o;
  o[0] = (bf16_t)v.x; o[1] = (bf16_t)v.y; o[2] = (bf16_t)v.z; o[3] = (bf16_t)v.w;
  reinterpret_cast<bf16x4*>(xb)[i] = o;
}

// ---------------- router: gate GEMV + grouped top-k + expert lists ----------------
__global__ __launch_bounds__(256) void router_kernel(
    const float* __restrict__ x, const float* __restrict__ gw,
    const float* __restrict__ bias, int* __restrict__ counts,
    int* __restrict__ tok_list, int* __restrict__ dst_list,
    float* __restrict__ wgt_list) {
  int t0 = blockIdx.x * 16;  // 16 tokens per block
  int tid = threadIdx.x;
  int e = tid & 63;
  int sub = tid >> 6;  // 0..3 ; this thread computes logits[e] for tokens t0+sub*4 .. +3

  const float4* gwe = reinterpret_cast<const float4*>(gw + (size_t)e * HDIM);
  const float4* x0 = reinterpret_cast<const float4*>(x + (size_t)(t0 + sub * 4 + 0) * HDIM);
  const float4* x1 = reinterpret_cast<const float4*>(x + (size_t)(t0 + sub * 4 + 1) * HDIM);
  const float4* x2 = reinterpret_cast<const float4*>(x + (size_t)(t0 + sub * 4 + 2) * HDIM);
  const float4* x3 = reinterpret_cast<const float4*>(x + (size_t)(t0 + sub * 4 + 3) * HDIM);
  float a0 = 0.f, a1 = 0.f, a2 = 0.f, a3 = 0.f;
  for (int h = 0; h < HDIM / 4; ++h) {
    float4 g = gwe[h];
    float4 v;
    v = x0[h]; a0 += g.x * v.x + g.y * v.y + g.z * v.z + g.w * v.w;
    v = x1[h]; a1 += g.x * v.x + g.y * v.y + g.z * v.z + g.w * v.w;
    v = x2[h]; a2 += g.x * v.x + g.y * v.y + g.z * v.z + g.w * v.w;
    v = x3[h]; a3 += g.x * v.x + g.y * v.y + g.z * v.z + g.w * v.w;
  }
  __shared__ float sc[16][64];
  sc[sub * 4 + 0][e] = a0;
  sc[sub * 4 + 1][e] = a1;
  sc[sub * 4 + 2][e] = a2;
  sc[sub * 4 + 3][e] = a3;
  __syncthreads();

  int lane = tid & 63;
  int wv = tid >> 6;
  for (int it = 0; it < 4; ++it) {
    int tt = wv * 4 + it;
    int t = t0 + tt;
    float logit = sc[tt][lane];
    float score = 1.0f / (1.0f + __expf(-logit));  // sigmoid
    float s = score + bias[lane];                  // selection score

    // top-2 per group of 8 lanes (butterfly merge of (m1,m2) pairs)
    float m1 = s, m2 = -INFINITY;
#pragma unroll
    for (int off = 1; off < 8; off <<= 1) {
      float o1 = __shfl_xor(m1, off);
      float o2 = __shfl_xor(m2, off);
      float hi = fmaxf(m1, o1);
      float lo = fminf(m1, o1);
      m2 = fmaxf(lo, fmaxf(m2, o2));
      m1 = hi;
    }
    float gscore = m1 + m2;  // identical across the 8 lanes of the group
    int g = lane >> 3;
    int grank = 0;
#pragma unroll
    for (int gg = 0; gg < 8; ++gg) {
      float og = __shfl(gscore, gg << 3);
      grank += ((og > gscore) || (og == gscore && gg < g)) ? 1 : 0;
    }
    float masked = (grank < TOPG) ? s : -INFINITY;

    // rank among 64 (descending, ties -> lower lane wins)
    int rank = 0;
    for (int l = 0; l < 64; ++l) {
      float ov = __shfl(masked, l);
      rank += ((ov > masked) || (ov == masked && l < lane)) ? 1 : 0;
    }
    bool sel = (rank < TOPKK) && (masked > -INFINITY);
    float part = sel ? score : 0.0f;
#pragma unroll
    for (int off = 32; off > 0; off >>= 1) part += __shfl_xor(part, off);
    if (sel) {
      int slot = atomicAdd(&counts[lane], 1);
      tok_list[lane * TOKENS + slot] = t;
      dst_list[lane * TOKENS + slot] = t * TOPKK + rank;  // compact h-row index
      wgt_list[lane * TOKENS + slot] = score / part;      // renormalized raw score
    }
  }
}

// ---------------- GEMM1: h = silu(x@Wg^T) * (x@Wu^T), per expert ----------------
// block: 256 thr (4 waves). tile = [256 tokens x 64 inter-cols], K=1024 staged BK=64.
// T14 async-STAGE pipeline: issue kt+1 loads -> compute kt -> barrier(drain) -> write -> barrier.
__global__ __launch_bounds__(256, 2) void gemm1_kernel(
    const bf16_t* __restrict__ xb, const float* __restrict__ w13,
    const int* __restrict__ counts, const int* __restrict__ tok_list,
    const int* __restrict__ dst_list, bf16_t* __restrict__ hbuf) {
  int e = blockIdx.z;
  int cnt = counts[e];
  int row0 = blockIdx.y * 256;
  if (row0 >= cnt) return;
  int rows = cnt - row0;
  if (rows > 256) rows = 256;
  int n0 = blockIdx.x * 64;  // over IDIM

  __shared__ alignas(16) char As[256 * 128];
  __shared__ alignas(16) char Bg[64 * 128];
  __shared__ alignas(16) char Bu[64 * 128];
  __shared__ int dstS[256];

  int tid = threadIdx.x;
  int tok = -1;
  if (tid < rows) {
    tok = tok_list[e * TOKENS + row0 + tid];
    dstS[tid] = dst_list[e * TOKENS + row0 + tid];
  }
  const bf16_t* xrow = (tok >= 0) ? (xb + (size_t)tok * HDIM) : (const bf16_t*)0;

  int lane = tid & 63;
  int wv = tid >> 6;

  f32x4 accg[4][4], accu[4][4];
#pragma unroll
  for (int i = 0; i < 4; ++i)
#pragma unroll
    for (int j = 0; j < 4; ++j) {
      accg[i][j] = f32x4{0.f, 0.f, 0.f, 0.f};
      accu[i][j] = f32x4{0.f, 0.f, 0.f, 0.f};
    }

  const float* w13e = w13 + (size_t)e * (2 * IDIM) * HDIM;
  int bn = tid >> 2;  // 0..63 : B row
  int bq = tid & 3;   // quarter of 64 k-elems
  const float* gsrc = w13e + (size_t)(n0 + bn) * HDIM + bq * 16;
  const float* usrc = w13e + (size_t)(IDIM + n0 + bn) * HDIM + bq * 16;
  int b0 = bn * 128 + bq * 32;

  // prefetch registers (live across compute; all statically indexed)
  bf16x8 ra[8];
  float4 rg[4], ru[4];

  // ---- prologue: load kt=0 into regs, write LDS, barrier ----
  if (tid < rows) {
#pragma unroll
    for (int j = 0; j < 8; ++j) ra[j] = *reinterpret_cast<const bf16x8*>(xrow + j * 8);
  }
  {
    const float4* g4 = reinterpret_cast<const float4*>(gsrc);
    const float4* u4 = reinterpret_cast<const float4*>(usrc);
#pragma unroll
    for (int j = 0; j < 4; ++j) { rg[j] = g4[j]; ru[j] = u4[j]; }
  }
  if (tid < rows) {
#pragma unroll
    for (int j = 0; j < 8; ++j)
      *reinterpret_cast<bf16x8*>(&As[SWZ(tid, tid * 128 + j * 16)]) = ra[j];
  }
  *reinterpret_cast<bf16x8*>(&Bg[SWZ(bn, b0)]) = pack_bf16x8(rg[0], rg[1]);
  *reinterpret_cast<bf16x8*>(&Bg[SWZ(bn, b0 + 16)]) = pack_bf16x8(rg[2], rg[3]);
  *reinterpret_cast<bf16x8*>(&Bu[SWZ(bn, b0)]) = pack_bf16x8(ru[0], ru[1]);
  *reinterpret_cast<bf16x8*>(&Bu[SWZ(bn, b0 + 16)]) = pack_bf16x8(ru[2], ru[3]);
  __syncthreads();

  for (int kt = 0; kt < 16; ++kt) {
    // ---- issue kt+1 loads BEFORE compute (async; latency hides under MFMA) ----
    if (kt < 15) {
      if (tid < rows) {
        const bf16_t* s = xrow + (kt + 1) * 64;
#pragma unroll
        for (int j = 0; j < 8; ++j) ra[j] = *reinterpret_cast<const bf16x8*>(s + j * 8);
      }
      const float4* g4 = reinterpret_cast<const float4*>(gsrc + (kt + 1) * 64);
      const float4* u4 = reinterpret_cast<const float4*>(usrc + (kt + 1) * 64);
#pragma unroll
      for (int j = 0; j < 4; ++j) { rg[j] = g4[j]; ru[j] = u4[j]; }
    }
    __builtin_amdgcn_sched_barrier(0);  // pin load-issue above compute

    // ---- compute 2 k-steps of 32 from LDS ----
#pragma unroll
    for (int ks = 0; ks < 2; ++ks) {
      int kb2 = (ks * 32 + ((lane >> 4) << 3)) * 2;  // byte offset of k within row
      bf16x8 a[4], bg[4], bu[4];
#pragma unroll
      for (int i = 0; i < 4; ++i) {
        int r = wv * 64 + i * 16 + (lane & 15);
        a[i] = *reinterpret_cast<const bf16x8*>(&As[SWZ(r, r * 128 + kb2)]);
      }
#pragma unroll
      for (int j = 0; j < 4; ++j) {
        int n = j * 16 + (lane & 15);
        bg[j] = *reinterpret_cast<const bf16x8*>(&Bg[SWZ(n, n * 128 + kb2)]);
        bu[j] = *reinterpret_cast<const bf16x8*>(&Bu[SWZ(n, n * 128 + kb2)]);
      }
#pragma unroll
      for (int i = 0; i < 4; ++i)
#pragma unroll
        for (int j = 0; j < 4; ++j) {
          accg[i][j] = __builtin_amdgcn_mfma_f32_16x16x32_bf16(a[i], bg[j], accg[i][j], 0, 0, 0);
          accu[i][j] = __builtin_amdgcn_mfma_f32_16x16x32_bf16(a[i], bu[j], accu[i][j], 0, 0, 0);
        }
    }
    __syncthreads();  // waves done reading LDS; implicit drain completes prefetch
    if (kt < 15) {
      if (tid < rows) {
#pragma unroll
        for (int j = 0; j < 8; ++j)
          *reinterpret_cast<bf16x8*>(&As[SWZ(tid, tid * 128 + j * 16)]) = ra[j];
      }
      *reinterpret_cast<bf16x8*>(&Bg[SWZ(bn, b0)]) = pack_bf16x8(rg[0], rg[1]);
      *reinterpret_cast<bf16x8*>(&Bg[SWZ(bn, b0 + 16)]) = pack_bf16x8(rg[2], rg[3]);
      *reinterpret_cast<bf16x8*>(&Bu[SWZ(bn, b0)]) = pack_bf16x8(ru[0], ru[1]);
      *reinterpret_cast<bf16x8*>(&Bu[SWZ(bn, b0 + 16)]) = pack_bf16x8(ru[2], ru[3]);
      __syncthreads();
    }
  }
  // ---- epilogue: SwiGLU, store h as bf16 ----
#pragma unroll
  for (int i = 0; i < 4; ++i) {
    int mbase = wv * 64 + i * 16 + ((lane >> 4) << 2);
#pragma unroll
    for (int r = 0; r < 4; ++r) {
      int m = mbase + r;
      if (m < rows) {
        int dst = dstS[m];
        bf16_t* hrow = hbuf + (size_t)dst * IDIM + n0;
#pragma unroll
        for (int j = 0; j < 4; ++j) {
          float gv = accg[i][j][r];
          float uv = accu[i][j][r];
          float hv = (gv / (1.0f + __expf(-gv))) * uv;
          hrow[j * 16 + (lane & 15)] = (bf16_t)hv;
        }
      }
    }
  }
}

// ---------------- GEMM2: y += wgt * (h @ w2^T), per expert ----------------
__global__ __launch_bounds__(256, 2) void gemm2_kernel(
    const bf16_t* __restrict__ hbuf, const float* __restrict__ w2,
    const int* __restrict__ counts, const int* __restrict__ tok_list,
    const int* __restrict__ dst_list, const float* __restrict__ wgt_list,
    float* __restrict__ y) {
  int e = blockIdx.z;
  int cnt = counts[e];
  int row0 = blockIdx.y * 256;
  if (row0 >= cnt) return;
  int rows = cnt - row0;
  if (rows > 256) rows = 256;
  int n0 = blockIdx.x * 64;  // over HDIM

  __shared__ alignas(16) char As[256 * 128];
  __shared__ alignas(16) char Bs[64 * 128];
  __shared__ int tokS[256];
  __shared__ float wS[256];

  int tid = threadIdx.x;
  int dst = -1;
  if (tid < rows) {
    tokS[tid] = tok_list[e * TOKENS + row0 + tid];
    dst = dst_list[e * TOKENS + row0 + tid];
    wS[tid] = wgt_list[e * TOKENS + row0 + tid];
  }
  const bf16_t* hrow = (dst >= 0) ? (hbuf + (size_t)dst * IDIM) : (const bf16_t*)0;

  int lane = tid & 63;
  int wv = tid >> 6;
  f32x4 acc[4][4];
#pragma unroll
  for (int i = 0; i < 4; ++i)
#pragma unroll
    for (int j = 0; j < 4; ++j) acc[i][j] = f32x4{0.f, 0.f, 0.f, 0.f};

  const float* w2e = w2 + (size_t)e * HDIM * IDIM;
  int bn = tid >> 2;
  int bq = tid & 3;
  const float* bsrc = w2e + (size_t)(n0 + bn) * IDIM + bq * 16;
  int b0 = bn * 128 + bq * 32;

  // prefetch registers
  bf16x8 rh[8];
  float4 rb[4];

  // ---- prologue: kt=0 ----
  if (tid < rows) {
#pragma unroll
    for (int j = 0; j < 8; ++j) rh[j] = *reinterpret_cast<const bf16x8*>(hrow + j * 8);
  }
  {
    const float4* s4 = reinterpret_cast<const float4*>(bsrc);
#pragma unroll
    for (int j = 0; j < 4; ++j) rb[j] = s4[j];
  }
  if (tid < rows) {
#pragma unroll
    for (int j = 0; j < 8; ++j)
      *reinterpret_cast<bf16x8*>(&As[SWZ(tid, tid * 128 + j * 16)]) = rh[j];
  }
  *reinterpret_cast<bf16x8*>(&Bs[SWZ(bn, b0)]) = pack_bf16x8(rb[0], rb[1]);
  *reinterpret_cast<bf16x8*>(&Bs[SWZ(bn, b0 + 16)]) = pack_bf16x8(rb[2], rb[3]);
  __syncthreads();

  for (int kt = 0; kt < 8; ++kt) {  // K = 512
    if (kt < 7) {
      if (tid < rows) {
        const bf16_t* s = hrow + (kt + 1) * 64;
#pragma unroll
        for (int j = 0; j < 8; ++j) rh[j] = *reinterpret_cast<const bf16x8*>(s + j * 8);
      }
      const float4* s4 = reinterpret_cast<const float4*>(bsrc + (kt + 1) * 64);
#pragma unroll
      for (int j = 0; j < 4; ++j) rb[j] = s4[j];
    }
    __builtin_amdgcn_sched_barrier(0);

#pragma unroll
    for (int ks = 0; ks < 2; ++ks) {
      int kb2 = (ks * 32 + ((lane >> 4) << 3)) * 2;
      bf16x8 a[4], b[4];
#pragma unroll
      for (int i = 0; i < 4; ++i) {
        int r = wv * 64 + i * 16 + (lane & 15);
        a[i] = *reinterpret_cast<const bf16x8*>(&As[SWZ(r, r * 128 + kb2)]);
      }
#pragma unroll
      for (int j = 0; j < 4; ++j) {
        int n = j * 16 + (lane & 15);
        b[j] = *reinterpret_cast<const bf16x8*>(&Bs[SWZ(n, n * 128 + kb2)]);
      }
#pragma unroll
      for (int i = 0; i < 4; ++i)
#pragma unroll
        for (int j = 0; j < 4; ++j)
          acc[i][j] = __builtin_amdgcn_mfma_f32_16x16x32_bf16(a[i], b[j], acc[i][j], 0, 0, 0);
    }
    __syncthreads();
    if (kt < 7) {
      if (tid < rows) {
#pragma unroll
        for (int j = 0; j < 8; ++j)
          *reinterpret_cast<bf16x8*>(&As[SWZ(tid, tid * 128 + j * 16)]) = rh[j];
      }
      *reinterpret_cast<bf16x8*>(&Bs[SWZ(bn, b0)]) = pack_bf16x8(rb[0], rb[1]);
      *reinterpret_cast<bf16x8*>(&Bs[SWZ(bn, b0 + 16)]) = pack_bf16x8(rb[2], rb[3]);
      __syncthreads();
    }
  }
  // ---- epilogue: scaled atomic accumulate into y ----
#pragma unroll
  for (int i = 0; i < 4; ++i) {
    int mbase = wv * 64 + i * 16 + ((lane >> 4) << 2);
#pragma unroll
    for (int r = 0; r < 4; ++r) {
      int m = mbase + r;
      if (m < rows) {
        float wgt = wS[m];
        float* yrow = y + (size_t)tokS[m] * HDIM + n0;
#pragma unroll
        for (int j = 0; j < 4; ++j) {
          atomicAdd(&yrow[j * 16 + (lane & 15)], acc[i][j][r] * wgt);
        }
      }
    }
  }
}

extern "C" void kernel_launch(void* const* d_in, const int* in_sizes, int n_in,
                              void* d_out, int out_size, void* d_ws, size_t ws_size,
                              hipStream_t stream) {
  const float* x = (const float*)d_in[0];
  const float* gw = (const float*)d_in[1];
  const float* bias = (const float*)d_in[2];
  const float* w13 = (const float*)d_in[3];
  const float* w2 = (const float*)d_in[4];
  float* y = (float*)d_out;

  char* ws = (char*)d_ws;
  const size_t LIST = (size_t)NEXP * TOKENS * 4;  // 512 KB
  int* counts = (int*)ws;                         // 1 KB reserved
  int* tok_list = (int*)(ws + 1024);
  int* dst_list = (int*)(ws + 1024 + LIST);
  float* wgt_list = (float*)(ws + 1024 + 2 * LIST);
  bf16_t* xb = (bf16_t*)(ws + 1024 + 3 * LIST);                          // 4 MB
  bf16_t* hbuf = (bf16_t*)(ws + 1024 + 3 * LIST + (size_t)TOKENS * HDIM * 2);  // 16 MB

  hipMemsetAsync(counts, 0, 1024, stream);
  hipMemsetAsync(y, 0, (size_t)TOKENS * HDIM * sizeof(float), stream);
  cvt_x_kernel<<<dim3(TOKENS * HDIM / 4 / 256), 256, 0, stream>>>(x, xb);
  router_kernel<<<dim3(TOKENS / 16), 256, 0, stream>>>(x, gw, bias, counts, tok_list,
                                                       dst_list, wgt_list);
  gemm1_kernel<<<dim3(IDIM / 64, 8, NEXP), 256, 0, stream>>>(xb, w13, counts, tok_list,
                                                             dst_list, hbuf);
  gemm2_kernel<<<dim3(HDIM / 64, 8, NEXP), 256, 0, stream>>>(hbuf, w2, counts, tok_list,
                                                             dst_list, wgt_list, y);
}